// Round 7
// baseline (456.927 us; speedup 1.0000x reference)
//
#include <hip/hip_runtime.h>
#include <hip/hip_bf16.h>

// B=8, N=2048, D=384, R=64, H=W=256.
// Inputs:  x (B,N,D) f32, segments (B,H,W) i32, prototypes (1,R,D) f32.
// Outputs (f32, concat): out (B,N,D) | segments (B,H,W) | loss (1) | C (B,N,R)
//
// Pooling = two barrier-free MFMA GEMM passes:
//   k_qk: P = mask .* (Chat Chat^T) per batch, bf16, materialized in ws (64MB,
//         L3-resident). Per-row factor cinv_n cancels in row normalization, so
//         Q=K=Kbf. Masked rowsum accumulated to rs via shuffle+atomicAdd.
//   k_pv: out = diag(1/rs) P X. A-frags stream from row-major P (lane=row,
//         vector bf16x8), B-frags from precomputed xT bf16. No LDS/barriers.
#define NB 8
#define NN 2048
#define ND 384
#define NR 64
#define OUT_ELEMS (NB*NN*ND)        // 6291456
#define SEG_ELEMS (NB*256*256)      // 524288

typedef float  f32x4  __attribute__((ext_vector_type(4)));
typedef short  bf16x8 __attribute__((ext_vector_type(8)));

__device__ inline float wsum(float v){
  #pragma unroll
  for(int o=32;o;o>>=1) v += __shfl_xor(v,o,64);
  return v;
}
__device__ inline float wmax(float v){
  #pragma unroll
  for(int o=32;o;o>>=1) v = fmaxf(v,__shfl_xor(v,o,64));
  return v;
}
__device__ inline unsigned short f2bf(float f){
  unsigned u = __float_as_uint(f);
  return (unsigned short)((u + 0x8000u) >> 16);
}

// ---- normalize prototypes -> kn (f32, unit rows) ----
__global__ void k_proto(const float* __restrict__ protos, float* __restrict__ kn){
  int r = blockIdx.x, l = threadIdx.x;
  float v[6]; float ss = 0.f;
  #pragma unroll
  for(int i=0;i<6;i++){ v[i] = protos[r*ND + l*6 + i]; ss += v[i]*v[i]; }
  ss = wsum(ss);
  float inv = 1.f / fmaxf(sqrtf(ss), 1e-8f);
  #pragma unroll
  for(int i=0;i<6;i++) kn[r*ND + l*6 + i] = v[i]*inv;
}

// ---- segments -> node mask + prox bitmask rows (64 u32/node, in ws) ----
__global__ void k_seg(const int* __restrict__ seg, float* __restrict__ mask, unsigned* prox){
  int idx = blockIdx.x*256 + threadIdx.x;
  int b = idx >> 16, p = idx & 65535, i = p >> 8, j = p & 255;
  int s = seg[idx];
  int base = b << 11;
  mask[base + s] = 1.f;
  if(j < 255){
    int s2 = seg[idx+1];
    if(s != s2 && s != 0 && s2 != 0){
      atomicOr(&prox[((size_t)(base+s))*64  + (s2>>5)], 1u<<(s2&31));
      atomicOr(&prox[((size_t)(base+s2))*64 + (s >>5)], 1u<<(s &31));
    }
  }
  if(i < 255){
    int s2 = seg[idx+256];
    if(s != s2 && s != 0 && s2 != 0){
      atomicOr(&prox[((size_t)(base+s))*64  + (s2>>5)], 1u<<(s2&31));
      atomicOr(&prox[((size_t)(base+s2))*64 + (s >>5)], 1u<<(s &31));
    }
  }
}

// ---- Csim GEMM (xinv fused) + bf16 x-transpose emission ----
__global__ __launch_bounds__(256) void k_csim(const float* __restrict__ x,
                                              const float* __restrict__ kn,
                                              float* __restrict__ Sout,
                                              unsigned short* __restrict__ xTbf){
  __shared__ float xT[32*68];
  __shared__ float kT[32*68];
  __shared__ float xinvS[64];
  int t = threadIdx.x;
  int m0 = blockIdx.x * 64;
  float acc[4][4] = {};
  int mload = t>>2, koff = (t&3)*8;
  int mb = (t>>4)*4, rb = (t&15)*4;
  float ssq = 0.f;
  for(int c=0;c<12;c++){
    int k0 = c*32;
    __syncthreads();
    const float4* xg = (const float4*)(x + (size_t)(m0+mload)*ND + k0 + koff);
    float4 a = xg[0], bq = xg[1];
    ssq += a.x*a.x + a.y*a.y + a.z*a.z + a.w*a.w
         + bq.x*bq.x + bq.y*bq.y + bq.z*bq.z + bq.w*bq.w;
    xT[(koff+0)*68+mload]=a.x;  xT[(koff+1)*68+mload]=a.y;  xT[(koff+2)*68+mload]=a.z;  xT[(koff+3)*68+mload]=a.w;
    xT[(koff+4)*68+mload]=bq.x; xT[(koff+5)*68+mload]=bq.y; xT[(koff+6)*68+mload]=bq.z; xT[(koff+7)*68+mload]=bq.w;
    const float4* kg = (const float4*)(kn + mload*ND + k0 + koff);
    float4 ka = kg[0], kb = kg[1];
    kT[(koff+0)*68+mload]=ka.x; kT[(koff+1)*68+mload]=ka.y; kT[(koff+2)*68+mload]=ka.z; kT[(koff+3)*68+mload]=ka.w;
    kT[(koff+4)*68+mload]=kb.x; kT[(koff+5)*68+mload]=kb.y; kT[(koff+6)*68+mload]=kb.z; kT[(koff+7)*68+mload]=kb.w;
    __syncthreads();
    {
      int k2 = t>>3, mo = (t&7)*8;
      const float* src = &xT[k2*68 + mo];
      float4 aa = *(const float4*)src;
      float4 bb = *(const float4*)(src+4);
      uint4 o;
      o.x = (unsigned)f2bf(aa.x) | ((unsigned)f2bf(aa.y)<<16);
      o.y = (unsigned)f2bf(aa.z) | ((unsigned)f2bf(aa.w)<<16);
      o.z = (unsigned)f2bf(bb.x) | ((unsigned)f2bf(bb.y)<<16);
      o.w = (unsigned)f2bf(bb.z) | ((unsigned)f2bf(bb.w)<<16);
      int bb2 = m0 >> 11, ml = m0 & 2047;
      *(uint4*)(xTbf + ((size_t)(bb2*ND + k0 + k2))*NN + ml + mo) = o;
    }
    for(int k=0;k<32;k++){
      float xv[4], kv[4];
      *(float4*)xv = *(const float4*)&xT[k*68+mb];
      *(float4*)kv = *(const float4*)&kT[k*68+rb];
      #pragma unroll
      for(int mi=0;mi<4;mi++)
        #pragma unroll
        for(int ri=0;ri<4;ri++) acc[mi][ri] += xv[mi]*kv[ri];
    }
  }
  ssq += __shfl_xor(ssq,1,64);
  ssq += __shfl_xor(ssq,2,64);
  if((t&3)==0) xinvS[mload] = 1.f / fmaxf(sqrtf(ssq), 1e-8f);
  __syncthreads();
  #pragma unroll
  for(int mi=0;mi<4;mi++){
    float xin = xinvS[mb+mi];
    #pragma unroll
    for(int ri=0;ri<4;ri++)
      Sout[(size_t)(m0+mb+mi)*NR + rb + ri] = (acc[mi][ri]*xin + 1.f)*0.5f;
  }
}

// ---- rawS -> normalized s (in place) + colsum partial ----
__global__ __launch_bounds__(256) void k_snorm(float* Smat, float* __restrict__ colsum){
  __shared__ float sh[256];
  int w = threadIdx.x>>6, l = threadIdx.x&63;
  int n0 = blockIdx.x*32 + w*8;
  int b = (blockIdx.x*32) >> 11;
  float csacc = 0.f;
  for(int k=0;k<8;k++){
    int node = n0 + k;
    float raw = Smat[node*NR + l];
    float s = raw / wsum(raw);
    Smat[node*NR + l] = s;
    csacc += s;
  }
  sh[threadIdx.x] = csacc;
  __syncthreads();
  if(threadIdx.x < 64)
    atomicAdd(&colsum[(b<<6) + threadIdx.x],
              sh[threadIdx.x]+sh[threadIdx.x+64]+sh[threadIdx.x+128]+sh[threadIdx.x+192]);
}

// ---- DEC KL loss partials + C=softmax(s) in place + Kbf = bf16(C*cinv) ----
__global__ void k_lossfc(float* Smat, const float* __restrict__ colsum,
                         const float* __restrict__ mask, float* __restrict__ lossacc,
                         unsigned short* __restrict__ Kbf){
  __shared__ float shk[4], shm[4];
  int w = threadIdx.x>>6, l = threadIdx.x&63;
  int node = blockIdx.x*4 + w;
  int b = node >> 11;
  float s = Smat[node*NR + l];
  float csm = colsum[(b<<6) + l];
  float p = s*s/(csm + 1e-8f);
  float ps = wsum(p);
  float P = p/(ps + 1e-8f);
  float term = P*(logf(P + 1e-8f) - logf(s + 1e-8f));
  float kl = wsum(term);
  if(l==0){ float mv = mask[node]; shk[w] = kl*mv; shm[w] = mv; }
  float mx = wmax(s);
  float e = expf(s - mx);
  float Z = wsum(e);
  float c = e / Z;
  float cn2 = wsum(c*c);
  Smat[node*NR + l] = c;
  Kbf[(size_t)node*NR + l] = f2bf(c * rsqrtf(cn2));
  __syncthreads();
  if(threadIdx.x==0){
    atomicAdd(&lossacc[0], shk[0]+shk[1]+shk[2]+shk[3]);
    atomicAdd(&lossacc[1], shm[0]+shm[1]+shm[2]+shm[3]);
  }
}

// ---- segout + loss finalize ----
__global__ void k_segout(const int* __restrict__ seg, float* __restrict__ o,
                         const float* __restrict__ lossacc, float* __restrict__ outLoss){
  int i = blockIdx.x*256 + threadIdx.x;
  o[i] = (float)seg[i];
  if(i==0) outLoss[0] = lossacc[0]/(lossacc[1]+1e-8f);
}

// ---- pass A: P tile (64x64) = mask .* (Chat Chat^T), bf16 -> ws; rowsum -> rs ----
// grid 8192: b=bid&7, qt=(bid>>3)&31, kt=bid>>8. One barrier per block.
__global__ __launch_bounds__(256) void k_qk(const unsigned short* __restrict__ Kbf,
                                            const unsigned* __restrict__ prox,
                                            unsigned short* __restrict__ Pbf,
                                            float* __restrict__ rs){
  __shared__ short Plds[64*72];
  int tid = threadIdx.x;
  int w = tid>>6, l = tid&63, q = l>>4, li = l&15;
  int b  = blockIdx.x & 7;
  int qt = (blockIdx.x>>3) & 31;
  int kt = blockIdx.x >> 8;
  const unsigned short* Kb = Kbf + (size_t)b*NN*NR;

  // A frags: rows qt*64 + w*16 + li
  int arow = qt*64 + w*16 + li;
  bf16x8 af[2];
  af[0] = *(const bf16x8*)(Kb + (size_t)arow*NR + q*8);
  af[1] = *(const bf16x8*)(Kb + (size_t)arow*NR + 32 + q*8);
  f32x4 pacc[4] = {(f32x4)(0.f),(f32x4)(0.f),(f32x4)(0.f),(f32x4)(0.f)};
  #pragma unroll
  for(int f=0;f<4;f++){
    int brow = kt*64 + f*16 + li;
    bf16x8 b0 = *(const bf16x8*)(Kb + (size_t)brow*NR + q*8);
    bf16x8 b1 = *(const bf16x8*)(Kb + (size_t)brow*NR + 32 + q*8);
    pacc[f] = __builtin_amdgcn_mfma_f32_16x16x32_bf16(af[0], b0, pacc[f], 0,0,0);
    pacc[f] = __builtin_amdgcn_mfma_f32_16x16x32_bf16(af[1], b1, pacc[f], 0,0,0);
  }
  // mask + rowsum + pack to LDS
  #pragma unroll
  for(int r=0;r<4;r++){
    int lrow = w*16 + q*4 + r;                  // row within 64-tile
    int grow = qt*64 + lrow;                    // global row
    uint2 mw = *(const uint2*)(prox + ((size_t)(b*NN + grow))*64 + kt*2);
    if(qt==kt){                                 // diagonal bit
      if((lrow>>5)==0) mw.x |= 1u<<(lrow&31); else mw.y |= 1u<<(lrow&31);
    }
    float rsum = 0.f;
    #pragma unroll
    for(int f=0;f<4;f++){
      unsigned wd = (f<2) ? mw.x : mw.y;
      float v = ((wd >> ((f&1)*16 + li)) & 1u) ? pacc[f][r] : 0.f;
      rsum += v;
      Plds[lrow*72 + f*16 + li] = (short)f2bf(v);
    }
    rsum += __shfl_xor(rsum,1,64); rsum += __shfl_xor(rsum,2,64);
    rsum += __shfl_xor(rsum,4,64); rsum += __shfl_xor(rsum,8,64);
    if(li==0) atomicAdd(&rs[b*NN + grow], rsum);
  }
  __syncthreads();
  // staged coalesced store: 4 threads per row, 32B each
  {
    int row = tid>>2, sg = tid&3;
    const uint4* src = (const uint4*)&Plds[row*72 + sg*16];
    unsigned short* dst = Pbf + ((size_t)(b*NN + qt*64 + row))*NN + kt*64 + sg*16;
    uint4 v0 = src[0], v1 = *(const uint4*)((const short*)src + 8);
    *(uint4*)dst = v0;
    *(uint4*)(dst + 8) = v1;
  }
}

// ---- pass B: out = diag(1/rs) P X. Streaming GEMM, no LDS, no barriers ----
// grid 512: b=bid&7, nt=(bid>>3)&31, ds=bid>>8. Wave w: cols ds*192+w*48.
__global__ __launch_bounds__(256) void k_pv(const unsigned short* __restrict__ Pbf,
                                            const unsigned short* __restrict__ xTbf,
                                            const float* __restrict__ rs,
                                            float* __restrict__ out){
  int tid = threadIdx.x;
  int w = tid>>6, l = tid&63, q = l>>4, li = l&15;
  int b  = blockIdx.x & 7;
  int nt = (blockIdx.x>>3) & 31;
  int ds = blockIdx.x >> 8;
  int base = nt*64;
  int dcb = ds*192 + w*48;
  const unsigned short* Pb  = Pbf  + (size_t)b*NN*NN;
  const unsigned short* xTb = xTbf + (size_t)b*ND*NN;

  f32x4 acc[4][3];
  #pragma unroll
  for(int nc=0;nc<4;nc++)
    #pragma unroll
    for(int t=0;t<3;t++) acc[nc][t] = (f32x4)(0.f);

  const unsigned short* Ap = Pb + (size_t)(base + li)*NN + q*8;
  const unsigned short* Bp = xTb + (size_t)(dcb + li)*NN + q*8;

  #pragma unroll 4
  for(int k0=0; k0<NN; k0+=32){
    bf16x8 af[4], bf[3];
    #pragma unroll
    for(int nc=0;nc<4;nc++) af[nc] = *(const bf16x8*)(Ap + (size_t)nc*16*NN + k0);
    #pragma unroll
    for(int t=0;t<3;t++)    bf[t]  = *(const bf16x8*)(Bp + (size_t)t*16*NN + k0);
    #pragma unroll
    for(int nc=0;nc<4;nc++)
      #pragma unroll
      for(int t=0;t<3;t++)
        acc[nc][t] = __builtin_amdgcn_mfma_f32_16x16x32_bf16(af[nc], bf[t], acc[nc][t], 0,0,0);
  }

  #pragma unroll
  for(int nc=0;nc<4;nc++)
    #pragma unroll
    for(int r=0;r<4;r++){
      int row = base + nc*16 + q*4 + r;
      float inv = 1.f/(rs[b*NN + row] + 1e-8f);
      float* orow = out + ((size_t)(b*NN + row))*ND + dcb;
      #pragma unroll
      for(int t=0;t<3;t++)
        orow[t*16 + li] = acc[nc][t][r] * inv;
    }
}

extern "C" void kernel_launch(void* const* d_in, const int* in_sizes, int n_in,
                              void* d_out, int out_size, void* d_ws, size_t ws_size,
                              hipStream_t stream) {
  const float* x      = (const float*)d_in[0];
  const int*   seg    = (const int*)d_in[1];
  const float* protos = (const float*)d_in[2];

  float* out     = (float*)d_out;                  // (B,N,D)
  float* outSeg  = out + OUT_ELEMS;                // (B,H,W)
  float* outLoss = outSeg + SEG_ELEMS;             // scalar
  float* outC    = outLoss + 1;                    // (B,N,R)

  // ws layout (~83 MB)
  unsigned short* xTbf = (unsigned short*)d_ws;            // 8*384*2048 bf16 (12.6MB)
  unsigned short* Kbf  = xTbf + (size_t)NB*ND*NN;          // 8*2048*64 bf16 (2MB)
  unsigned short* Pbf  = Kbf + (size_t)NB*NN*NR;           // 8*2048*2048 bf16 (64MB)
  float* kn      = (float*)(Pbf + (size_t)NB*NN*NN);       // 24576 f32
  float* maskp   = kn + NR*ND;                             // 16384  -- zero region start
  float* colsum  = maskp + NB*NN;                          // 512
  float* lossacc = colsum + NB*NR;                         // 4
  float* rsbuf   = lossacc + 4;                            // 16384
  unsigned* prox = (unsigned*)(rsbuf + NB*NN);             // 8*2048*64 u32 (4MB)

  size_t zero_bytes = (size_t)(NB*NN + NB*NR + 4 + NB*NN)*4 + (size_t)NB*NN*64*4;
  hipMemsetAsync(maskp, 0, zero_bytes, stream);

  k_proto <<<dim3(NR),           dim3(64),  0, stream>>>(protos, kn);
  k_seg   <<<dim3(NB*65536/256), dim3(256), 0, stream>>>(seg, maskp, prox);
  k_csim  <<<dim3(NB*NN/64),     dim3(256), 0, stream>>>(x, kn, outC, xTbf);
  k_snorm <<<dim3(NB*NN/32),     dim3(256), 0, stream>>>(outC, colsum);
  k_lossfc<<<dim3(NB*NN/4),      dim3(256), 0, stream>>>(outC, colsum, maskp, lossacc, Kbf);
  k_qk    <<<dim3(8192),         dim3(256), 0, stream>>>(Kbf, prox, Pbf, rsbuf);
  k_pv    <<<dim3(512),          dim3(256), 0, stream>>>(Pbf, xTbf, rsbuf, out);
  k_segout<<<dim3(SEG_ELEMS/256),dim3(256), 0, stream>>>(seg, outSeg, lossacc, outLoss);
}

// Round 8
// 351.872 us; speedup vs baseline: 1.2986x; 1.2986x over previous
//
#include <hip/hip_runtime.h>
#include <hip/hip_bf16.h>

// B=8, N=2048, D=384, R=64, H=W=256.
// Inputs:  x (B,N,D) f32, segments (B,H,W) i32, prototypes (1,R,D) f32.
// Outputs (f32, concat): out (B,N,D) | segments (B,H,W) | loss (1) | C (B,N,R)
//
// Pipeline (8 dispatches, ZERO same-address atomic hotspots):
//   memset(maskp+prox) ; k_proto ; k_seg ; k_csim (S normalized + colsum
//   partials + bf16 xT) ; k_lossfc (loss partials + C + Kbf) ; k_qk (P=mask.*
//   ChatChat^T bf16 -> ws) ; k_pv (out = diag(1/(P*1)) P X, rowsum via
//   ones-fragment MFMA) ; k_segout (+ loss final reduce in block 0).
#define NB 8
#define NN 2048
#define ND 384
#define NR 64
#define OUT_ELEMS (NB*NN*ND)        // 6291456
#define SEG_ELEMS (NB*256*256)      // 524288
#define NBLK_LOSS (NB*NN/4)         // 4096

typedef float  f32x4  __attribute__((ext_vector_type(4)));
typedef short  bf16x8 __attribute__((ext_vector_type(8)));

__device__ inline float wsum(float v){
  #pragma unroll
  for(int o=32;o;o>>=1) v += __shfl_xor(v,o,64);
  return v;
}
__device__ inline float wmax(float v){
  #pragma unroll
  for(int o=32;o;o>>=1) v = fmaxf(v,__shfl_xor(v,o,64));
  return v;
}
__device__ inline unsigned short f2bf(float f){
  unsigned u = __float_as_uint(f);
  return (unsigned short)((u + 0x8000u) >> 16);
}

// ---- normalize prototypes -> kn (f32, unit rows) ----
__global__ void k_proto(const float* __restrict__ protos, float* __restrict__ kn){
  int r = blockIdx.x, l = threadIdx.x;
  float v[6]; float ss = 0.f;
  #pragma unroll
  for(int i=0;i<6;i++){ v[i] = protos[r*ND + l*6 + i]; ss += v[i]*v[i]; }
  ss = wsum(ss);
  float inv = 1.f / fmaxf(sqrtf(ss), 1e-8f);
  #pragma unroll
  for(int i=0;i<6;i++) kn[r*ND + l*6 + i] = v[i]*inv;
}

// ---- segments -> node mask + prox bitmask rows (64 u32/node) ----
__global__ void k_seg(const int* __restrict__ seg, float* __restrict__ mask, unsigned* prox){
  int idx = blockIdx.x*256 + threadIdx.x;
  int b = idx >> 16, p = idx & 65535, i = p >> 8, j = p & 255;
  int s = seg[idx];
  int base = b << 11;
  mask[base + s] = 1.f;
  if(j < 255){
    int s2 = seg[idx+1];
    if(s != s2 && s != 0 && s2 != 0){
      atomicOr(&prox[((size_t)(base+s))*64  + (s2>>5)], 1u<<(s2&31));
      atomicOr(&prox[((size_t)(base+s2))*64 + (s >>5)], 1u<<(s &31));
    }
  }
  if(i < 255){
    int s2 = seg[idx+256];
    if(s != s2 && s != 0 && s2 != 0){
      atomicOr(&prox[((size_t)(base+s))*64  + (s2>>5)], 1u<<(s2&31));
      atomicOr(&prox[((size_t)(base+s2))*64 + (s >>5)], 1u<<(s &31));
    }
  }
}

// ---- Csim GEMM: writes NORMALIZED s, colsum partials, bf16 xT ----
__global__ __launch_bounds__(256) void k_csim(const float* __restrict__ x,
                                              const float* __restrict__ kn,
                                              float* __restrict__ Sout,
                                              unsigned short* __restrict__ xTbf,
                                              float* __restrict__ part){
  __shared__ float xT[32*68];
  __shared__ float kT[32*68];
  __shared__ float xinvS[64];
  __shared__ float csh[16*64];
  int t = threadIdx.x;
  int m0 = blockIdx.x * 64;
  float acc[4][4] = {};
  int mload = t>>2, koff = (t&3)*8;
  int mb = (t>>4)*4, rb = (t&15)*4;
  float ssq = 0.f;
  for(int c=0;c<12;c++){
    int k0 = c*32;
    __syncthreads();
    const float4* xg = (const float4*)(x + (size_t)(m0+mload)*ND + k0 + koff);
    float4 a = xg[0], bq = xg[1];
    ssq += a.x*a.x + a.y*a.y + a.z*a.z + a.w*a.w
         + bq.x*bq.x + bq.y*bq.y + bq.z*bq.z + bq.w*bq.w;
    xT[(koff+0)*68+mload]=a.x;  xT[(koff+1)*68+mload]=a.y;  xT[(koff+2)*68+mload]=a.z;  xT[(koff+3)*68+mload]=a.w;
    xT[(koff+4)*68+mload]=bq.x; xT[(koff+5)*68+mload]=bq.y; xT[(koff+6)*68+mload]=bq.z; xT[(koff+7)*68+mload]=bq.w;
    const float4* kg = (const float4*)(kn + mload*ND + k0 + koff);
    float4 ka = kg[0], kb = kg[1];
    kT[(koff+0)*68+mload]=ka.x; kT[(koff+1)*68+mload]=ka.y; kT[(koff+2)*68+mload]=ka.z; kT[(koff+3)*68+mload]=ka.w;
    kT[(koff+4)*68+mload]=kb.x; kT[(koff+5)*68+mload]=kb.y; kT[(koff+6)*68+mload]=kb.z; kT[(koff+7)*68+mload]=kb.w;
    __syncthreads();
    {
      int k2 = t>>3, mo = (t&7)*8;
      const float* src = &xT[k2*68 + mo];
      float4 aa = *(const float4*)src;
      float4 bb = *(const float4*)(src+4);
      uint4 o;
      o.x = (unsigned)f2bf(aa.x) | ((unsigned)f2bf(aa.y)<<16);
      o.y = (unsigned)f2bf(aa.z) | ((unsigned)f2bf(aa.w)<<16);
      o.z = (unsigned)f2bf(bb.x) | ((unsigned)f2bf(bb.y)<<16);
      o.w = (unsigned)f2bf(bb.z) | ((unsigned)f2bf(bb.w)<<16);
      int bb2 = m0 >> 11, ml = m0 & 2047;
      *(uint4*)(xTbf + ((size_t)(bb2*ND + k0 + k2))*NN + ml + mo) = o;
    }
    for(int k=0;k<32;k++){
      float xv[4], kv[4];
      *(float4*)xv = *(const float4*)&xT[k*68+mb];
      *(float4*)kv = *(const float4*)&kT[k*68+rb];
      #pragma unroll
      for(int mi=0;mi<4;mi++)
        #pragma unroll
        for(int ri=0;ri<4;ri++) acc[mi][ri] += xv[mi]*kv[ri];
    }
  }
  ssq += __shfl_xor(ssq,1,64);
  ssq += __shfl_xor(ssq,2,64);
  if((t&3)==0) xinvS[mload] = 1.f / fmaxf(sqrtf(ssq), 1e-8f);
  __syncthreads();
  // epilogue: raw -> row-normalized s (rowsum over the 16-lane rb group)
  float sv[4][4];
  #pragma unroll
  for(int mi=0;mi<4;mi++){
    float xin = xinvS[mb+mi];
    float rsum = 0.f;
    #pragma unroll
    for(int ri=0;ri<4;ri++){
      float vv = (acc[mi][ri]*xin + 1.f)*0.5f;
      sv[mi][ri] = vv; rsum += vv;
    }
    rsum += __shfl_xor(rsum,1,64);
    rsum += __shfl_xor(rsum,2,64);
    rsum += __shfl_xor(rsum,4,64);
    rsum += __shfl_xor(rsum,8,64);
    float inv = 1.f/rsum;
    #pragma unroll
    for(int ri=0;ri<4;ri++) sv[mi][ri] *= inv;
    *(float4*)&Sout[(size_t)(m0+mb+mi)*NR + rb] = *(const float4*)sv[mi];
  }
  // colsum partial for this block's 64 nodes (no atomics: fully-written array)
  {
    float4 pc;
    pc.x = sv[0][0]+sv[1][0]+sv[2][0]+sv[3][0];
    pc.y = sv[0][1]+sv[1][1]+sv[2][1]+sv[3][1];
    pc.z = sv[0][2]+sv[1][2]+sv[2][2]+sv[3][2];
    pc.w = sv[0][3]+sv[1][3]+sv[2][3]+sv[3][3];
    *(float4*)&csh[(t>>4)*64 + rb] = pc;
  }
  __syncthreads();
  if(t < 64){
    float a = 0.f;
    #pragma unroll
    for(int g=0;g<16;g++) a += csh[g*64 + t];
    part[(size_t)blockIdx.x*64 + t] = a;        // part[b*32+chunk][r]
  }
}

// ---- DEC KL loss (partial stores) + C=softmax(s) in place + Kbf ----
__global__ void k_lossfc(float* Smat, const float* __restrict__ part,
                         const float* __restrict__ mask,
                         float* __restrict__ klp, float* __restrict__ mp,
                         unsigned short* __restrict__ Kbf){
  __shared__ float shk[4], shm[4];
  int w = threadIdx.x>>6, l = threadIdx.x&63;
  int node = blockIdx.x*4 + w;
  int b = node >> 11;
  float s = Smat[(size_t)node*NR + l];
  float csm = 0.f;
  #pragma unroll
  for(int c=0;c<32;c++) csm += part[(size_t)((b<<5)+c)*64 + l];
  float p = s*s/(csm + 1e-8f);
  float ps = wsum(p);
  float P = p/(ps + 1e-8f);
  float term = P*(logf(P + 1e-8f) - logf(s + 1e-8f));
  float kl = wsum(term);
  if(l==0){ float mv = mask[node]; shk[w] = kl*mv; shm[w] = mv; }
  float mx = wmax(s);
  float e = expf(s - mx);
  float Z = wsum(e);
  float c = e / Z;
  float cn2 = wsum(c*c);
  Smat[(size_t)node*NR + l] = c;
  Kbf[(size_t)node*NR + l] = f2bf(c * rsqrtf(cn2));
  __syncthreads();
  if(threadIdx.x==0){
    klp[blockIdx.x] = shk[0]+shk[1]+shk[2]+shk[3];
    mp [blockIdx.x] = shm[0]+shm[1]+shm[2]+shm[3];
  }
}

// ---- pass A: P tile (64x64) = mask .* (Chat Chat^T), bf16 -> ws ----
// grid 8192: b=bid&7, qt=(bid>>3)&31, kt=bid>>8. One barrier per block.
__global__ __launch_bounds__(256) void k_qk(const unsigned short* __restrict__ Kbf,
                                            const unsigned* __restrict__ prox,
                                            unsigned short* __restrict__ Pbf){
  __shared__ short Plds[64*72];
  int tid = threadIdx.x;
  int w = tid>>6, l = tid&63, q = l>>4, li = l&15;
  int b  = blockIdx.x & 7;
  int qt = (blockIdx.x>>3) & 31;
  int kt = blockIdx.x >> 8;
  const unsigned short* Kb = Kbf + (size_t)b*NN*NR;

  int arow = qt*64 + w*16 + li;
  bf16x8 af[2];
  af[0] = *(const bf16x8*)(Kb + (size_t)arow*NR + q*8);
  af[1] = *(const bf16x8*)(Kb + (size_t)arow*NR + 32 + q*8);
  f32x4 pacc[4] = {(f32x4)(0.f),(f32x4)(0.f),(f32x4)(0.f),(f32x4)(0.f)};
  #pragma unroll
  for(int f=0;f<4;f++){
    int brow = kt*64 + f*16 + li;
    bf16x8 b0 = *(const bf16x8*)(Kb + (size_t)brow*NR + q*8);
    bf16x8 b1 = *(const bf16x8*)(Kb + (size_t)brow*NR + 32 + q*8);
    pacc[f] = __builtin_amdgcn_mfma_f32_16x16x32_bf16(af[0], b0, pacc[f], 0,0,0);
    pacc[f] = __builtin_amdgcn_mfma_f32_16x16x32_bf16(af[1], b1, pacc[f], 0,0,0);
  }
  #pragma unroll
  for(int r=0;r<4;r++){
    int lrow = w*16 + q*4 + r;
    int grow = qt*64 + lrow;
    uint2 mw = *(const uint2*)(prox + ((size_t)(b*NN + grow))*64 + kt*2);
    if(qt==kt){
      if((lrow>>5)==0) mw.x |= 1u<<(lrow&31); else mw.y |= 1u<<(lrow&31);
    }
    #pragma unroll
    for(int f=0;f<4;f++){
      unsigned wd = (f<2) ? mw.x : mw.y;
      float v = ((wd >> ((f&1)*16 + li)) & 1u) ? pacc[f][r] : 0.f;
      Plds[lrow*72 + f*16 + li] = (short)f2bf(v);
    }
  }
  __syncthreads();
  {
    int row = tid>>2, sg = tid&3;
    const uint4* src = (const uint4*)&Plds[row*72 + sg*16];
    unsigned short* dst = Pbf + ((size_t)(b*NN + qt*64 + row))*NN + kt*64 + sg*16;
    uint4 v0 = src[0], v1 = *(const uint4*)((const short*)src + 8);
    *(uint4*)dst = v0;
    *(uint4*)(dst + 8) = v1;
  }
}

// ---- pass B: out = diag(1/(P*1)) P X. Streaming, no LDS/barriers/atomics ----
// rowsum via ones-fragment MFMA: D=P*1 lands rowsums in exactly the C-layout
// reg/lane that normalizes that row. grid 512: b=bid&7, nt, ds.
__global__ __launch_bounds__(256) void k_pv(const unsigned short* __restrict__ Pbf,
                                            const unsigned short* __restrict__ xTbf,
                                            float* __restrict__ out){
  int tid = threadIdx.x;
  int w = tid>>6, l = tid&63, q = l>>4, li = l&15;
  int b  = blockIdx.x & 7;
  int nt = (blockIdx.x>>3) & 31;
  int ds = blockIdx.x >> 8;
  int base = nt*64;
  int dcb = ds*192 + w*48;
  const unsigned short* Pb  = Pbf  + (size_t)b*NN*NN;
  const unsigned short* xTb = xTbf + (size_t)b*ND*NN;

  f32x4 acc[4][3];
  #pragma unroll
  for(int nc=0;nc<4;nc++)
    #pragma unroll
    for(int t=0;t<3;t++) acc[nc][t] = (f32x4)(0.f);
  f32x4 rsacc[4] = {(f32x4)(0.f),(f32x4)(0.f),(f32x4)(0.f),(f32x4)(0.f)};
  bf16x8 ones;
  #pragma unroll
  for(int i=0;i<8;i++) ones[i] = (short)0x3F80;   // bf16 1.0

  const unsigned short* Ap = Pb + (size_t)(base + li)*NN + q*8;
  const unsigned short* Bp = xTb + (size_t)(dcb + li)*NN + q*8;

  #pragma unroll 4
  for(int k0=0; k0<NN; k0+=32){
    bf16x8 af[4], bfv[3];
    #pragma unroll
    for(int nc=0;nc<4;nc++) af[nc] = *(const bf16x8*)(Ap + (size_t)nc*16*NN + k0);
    #pragma unroll
    for(int t=0;t<3;t++)    bfv[t] = *(const bf16x8*)(Bp + (size_t)t*16*NN + k0);
    #pragma unroll
    for(int nc=0;nc<4;nc++){
      #pragma unroll
      for(int t=0;t<3;t++)
        acc[nc][t] = __builtin_amdgcn_mfma_f32_16x16x32_bf16(af[nc], bfv[t], acc[nc][t], 0,0,0);
      rsacc[nc] = __builtin_amdgcn_mfma_f32_16x16x32_bf16(af[nc], ones, rsacc[nc], 0,0,0);
    }
  }

  #pragma unroll
  for(int nc=0;nc<4;nc++)
    #pragma unroll
    for(int r=0;r<4;r++){
      int row = base + nc*16 + q*4 + r;
      float inv = 1.f/(rsacc[nc][r] + 1e-8f);
      float* orow = out + ((size_t)(b*NN + row))*ND + dcb;
      #pragma unroll
      for(int t=0;t<3;t++)
        orow[t*16 + li] = acc[nc][t][r] * inv;
    }
}

// ---- segout; block 0 also reduces the loss partials ----
__global__ void k_segout(const int* __restrict__ seg, float* __restrict__ o,
                         const float* __restrict__ klp, const float* __restrict__ mp,
                         float* __restrict__ outLoss){
  int tid = threadIdx.x;
  int i = blockIdx.x*256 + tid;
  o[i] = (float)seg[i];
  if(blockIdx.x==0){
    __shared__ float sa[4], sm[4];
    float a=0.f, m=0.f;
    for(int k=tid; k<NBLK_LOSS; k+=256){ a += klp[k]; m += mp[k]; }
    a = wsum(a); m = wsum(m);
    if((tid&63)==0){ sa[tid>>6]=a; sm[tid>>6]=m; }
    __syncthreads();
    if(tid==0)
      outLoss[0] = (sa[0]+sa[1]+sa[2]+sa[3])/((sm[0]+sm[1]+sm[2]+sm[3])+1e-8f);
  }
}

extern "C" void kernel_launch(void* const* d_in, const int* in_sizes, int n_in,
                              void* d_out, int out_size, void* d_ws, size_t ws_size,
                              hipStream_t stream) {
  const float* x      = (const float*)d_in[0];
  const int*   seg    = (const int*)d_in[1];
  const float* protos = (const float*)d_in[2];

  float* out     = (float*)d_out;                  // (B,N,D)
  float* outSeg  = out + OUT_ELEMS;                // (B,H,W)
  float* outLoss = outSeg + SEG_ELEMS;             // scalar
  float* outC    = outLoss + 1;                    // (B,N,R)

  // ws layout (~83 MB)
  unsigned short* xTbf = (unsigned short*)d_ws;            // 8*384*2048 bf16 (12.6MB)
  unsigned short* Kbf  = xTbf + (size_t)NB*ND*NN;          // 8*2048*64 bf16 (2MB)
  unsigned short* Pbf  = Kbf + (size_t)NB*NN*NR;           // 8*2048*2048 bf16 (64MB)
  float* kn      = (float*)(Pbf + (size_t)NB*NN*NN);       // 24576 f32
  float* maskp   = kn + NR*ND;                             // 16384  -- zero region start
  unsigned* prox = (unsigned*)(maskp + NB*NN);             // 8*2048*64 u32 (4MB) -- zero region end
  float* part    = (float*)(prox + (size_t)NB*NN*64);      // 8*32*64 (fully written)
  float* klp     = part + NB*32*64;                        // 4096 (fully written)
  float* mp      = klp + NBLK_LOSS;                        // 4096 (fully written)

  size_t zero_bytes = (size_t)NB*NN*4 + (size_t)NB*NN*64*4;   // maskp + prox
  hipMemsetAsync(maskp, 0, zero_bytes, stream);

  k_proto <<<dim3(NR),           dim3(64),  0, stream>>>(protos, kn);
  k_seg   <<<dim3(NB*65536/256), dim3(256), 0, stream>>>(seg, maskp, prox);
  k_csim  <<<dim3(NB*NN/64),     dim3(256), 0, stream>>>(x, kn, outC, xTbf, part);
  k_lossfc<<<dim3(NBLK_LOSS),    dim3(256), 0, stream>>>(outC, part, maskp, klp, mp, Kbf);
  k_qk    <<<dim3(8192),         dim3(256), 0, stream>>>(Kbf, prox, Pbf);
  k_pv    <<<dim3(512),          dim3(256), 0, stream>>>(Pbf, xTbf, out);
  k_segout<<<dim3(SEG_ELEMS/256),dim3(256), 0, stream>>>(seg, outSeg, klp, mp, outLoss);
}